// Round 1
// baseline (1046.233 us; speedup 1.0000x reference)
//
#include <hip/hip_runtime.h>
#include <hip/hip_bf16.h>
#include <stdint.h>

typedef __bf16 bf16_t;
typedef __attribute__((ext_vector_type(8))) __bf16 bf16x8;
typedef __attribute__((ext_vector_type(4))) float f32x4;

#define B_  8
#define S_  1024
#define D_  1024
#define H_  16
#define HD_ 64
#define CD_ 512

typedef __attribute__((address_space(1))) const unsigned int* gas_ptr;
typedef __attribute__((address_space(3))) unsigned int* las_ptr;

__device__ __forceinline__ void gl2lds16(const void* g, void* l) {
    __builtin_amdgcn_global_load_lds((gas_ptr)(unsigned long long)g,
                                     (las_ptr)(unsigned long long)l, 16, 0, 0);
}

__device__ __forceinline__ float clamp30(float x) {
    return fminf(fmaxf(x, -30.f), 30.f);
}

// ---------------- K-1: dtype detect (0 = bf16, 1 = f32) -------------------------------
__global__ void detect_kernel(const unsigned int* Wbits, int* flag) {
    __shared__ int cnt[64];
    int c = 0;
    for (int i = threadIdx.x; i < 512; i += 64) {
        unsigned int w = Wbits[i];
        unsigned int e = (w >> 7) & 0xFFu;   // exponent field of low half-word as bf16
        c += (e >= 0x66u && e <= 0x7Fu) ? 1 : 0;
    }
    cnt[threadIdx.x] = c;
    __syncthreads();
    if (threadIdx.x == 0) {
        int t = 0;
        for (int i = 0; i < 64; ++i) t += cnt[i];
        *flag = (t >= 280) ? 0 : 1;
    }
}

// ---------------- K0: canonicalize all inputs to bf16 ---------------------------------
#define CANON_TOTAL 28333568u
struct CanonArgs {
    const void* src[23];
    bf16_t* dst[23];
    unsigned int off[24];
    const int* flag;
};

__global__ __launch_bounds__(256) void canon_kernel(CanonArgs a) {
    const bool f32 = (*a.flag != 0);
    const unsigned int e = ((unsigned int)blockIdx.x * 256u + threadIdx.x) * 8u;
    if (e >= CANON_TOTAL) return;
    int t = 0;
    while (e >= a.off[t + 1]) ++t;
    const unsigned int le = e - a.off[t];
    bf16_t* d = a.dst[t] + le;
    if (f32) {
        const float* s = (const float*)a.src[t] + le;
        bf16x8 o;
#pragma unroll
        for (int j = 0; j < 8; ++j) o[j] = (bf16_t)s[j];
        *(bf16x8*)d = o;
    } else {
        *(uint4*)d = *(const uint4*)((const bf16_t*)a.src[t] + le);
    }
}

// ---------------- K1: transformed-code vectors ----------------------------------------
struct TCArgs {
    const bf16_t* code;
    const bf16_t* bglob;
    const bf16_t* wcw[4];
    const bf16_t* wcb[4];
    const bf16_t* lng[4];
    const bf16_t* lnb[4];
    float* tc;       // [4][1024]
    float* biasArr;  // [4][1024]
};

__global__ __launch_bounds__(256) void tc_kernel(TCArgs a) {
    const int p = blockIdx.x;
    const int tid = threadIdx.x;
    __shared__ float codeS[CD_];
    __shared__ float red[256];
    __shared__ float bcast[2];
    for (int c = tid; c < CD_; c += 256) codeS[c] = (float)a.code[c];
    __syncthreads();
    float y[4];
    const bf16_t* wcw = a.wcw[p];
    for (int j = 0; j < 4; ++j) {
        const int d = tid + j * 256;
        float acc = (float)a.wcb[p][d];
        const bf16x8* row = (const bf16x8*)(wcw + (size_t)d * CD_);
        for (int c8 = 0; c8 < CD_ / 8; ++c8) {
            bf16x8 v = row[c8];
#pragma unroll
            for (int t = 0; t < 8; ++t) acc += codeS[c8 * 8 + t] * (float)v[t];
        }
        y[j] = acc;
    }
    float s = y[0] + y[1] + y[2] + y[3];
    red[tid] = s;
    __syncthreads();
    for (int off = 128; off > 0; off >>= 1) {
        if (tid < off) red[tid] += red[tid + off];
        __syncthreads();
    }
    if (tid == 0) bcast[0] = red[0] * (1.0f / (float)D_);
    __syncthreads();
    const float mu = bcast[0];
    float sq = 0.f;
    for (int j = 0; j < 4; ++j) { float t = y[j] - mu; sq += t * t; }
    red[tid] = sq;
    __syncthreads();
    for (int off = 128; off > 0; off >>= 1) {
        if (tid < off) red[tid] += red[tid + off];
        __syncthreads();
    }
    if (tid == 0) bcast[1] = red[0] * (1.0f / (float)D_);
    __syncthreads();
    const float rstd = rsqrtf(bcast[1] + 1e-5f);
    const float scale = (p == 0) ? 0.125f : 1.0f;  // fold 1/sqrt(HD) into q path
    for (int j = 0; j < 4; ++j) {
        const int d = tid + j * 256;
        float tcv = ((y[j] - mu) * rstd * (float)a.lng[p][d] + (float)a.lnb[p][d]) * scale;
        a.tc[p * D_ + d] = tcv;
        a.biasArr[p * D_ + d] = (float)a.bglob[d] * scale;
    }
}

// ---------------- K2: Wp[p][n][k] = W[n][k] * tc[p][k] --------------------------------
__global__ __launch_bounds__(256) void wscale_kernel(const bf16_t* __restrict__ W,
                                                     const float* __restrict__ tc,
                                                     bf16_t* __restrict__ Wp) {
    const size_t idx = (size_t)blockIdx.x * 256 + threadIdx.x;
    const size_t e = idx * 8;
    const int p = (int)(e >> 20);
    const size_t rem = e & 1048575;
    const int k = (int)(rem & 1023);
    bf16x8 w = *(const bf16x8*)(W + rem);
    const float* t = tc + p * 1024 + k;
    bf16x8 o;
#pragma unroll
    for (int j = 0; j < 8; ++j) o[j] = (bf16_t)((float)w[j] * t[j]);
    *(bf16x8*)(Wp + e) = o;
}

// ---------------- K3/K8: bt-GEMM  C = A @ Wp[p]^T + bias[p] ---------------------------
__global__ __launch_bounds__(256) void gemm_bt(const bf16_t* __restrict__ A0,
                                               const bf16_t* __restrict__ A1,
                                               const bf16_t* __restrict__ A2,
                                               const bf16_t* __restrict__ WpAll,
                                               const float* __restrict__ biasAll,
                                               void* Cbase, int pBase, int dualOut,
                                               const int* flagp) {
    constexpr int Kd = 1024, Nd = 1024;
    __shared__ __align__(16) bf16_t As[128 * 32];
    __shared__ __align__(16) bf16_t Bs[128 * 32];
    const int tid = threadIdx.x;
    const int pl = blockIdx.y >> 6;
    const int p = pBase + pl;
    const bf16_t* A = (pl == 0) ? A0 : ((pl == 1) ? A1 : A2);
    const bf16_t* Bw = WpAll + (size_t)p * 1024 * 1024;
    const size_t cOff = (size_t)pl * 8388608;
    const int rowBase = (blockIdx.y & 63) * 128;
    const int colBase = blockIdx.x * 128;
    const int lane = tid & 63;
    const int wv = tid >> 6;
    const int wm = wv >> 1, wn = wv & 1;
    const int qd = lane >> 4, cl = lane & 15;

    f32x4 acc[4][4];
#pragma unroll
    for (int tn = 0; tn < 4; ++tn) {
        float bv = biasAll[p * 1024 + colBase + wn * 64 + tn * 16 + cl];
#pragma unroll
        for (int tm = 0; tm < 4; ++tm) acc[tm][tn] = (f32x4){bv, bv, bv, bv};
    }

    for (int kb = 0; kb < Kd; kb += 32) {
#pragma unroll
        for (int cc = 0; cc < 2; ++cc) {
            const int s = tid + cc * 256;
            const int rw = s >> 2;
            const int co = (s & 3) * 8;
            gl2lds16(A + (size_t)(rowBase + rw) * Kd + kb + co,
                     (char*)As + wv * 1024 + cc * 4096);
            gl2lds16(Bw + (size_t)(colBase + rw) * Kd + kb + co,
                     (char*)Bs + wv * 1024 + cc * 4096);
        }
        __syncthreads();
        bf16x8 aF[4], bF[4];
#pragma unroll
        for (int tm = 0; tm < 4; ++tm)
            aF[tm] = *(const bf16x8*)&As[(wm * 64 + tm * 16 + cl) * 32 + qd * 8];
#pragma unroll
        for (int tn = 0; tn < 4; ++tn)
            bF[tn] = *(const bf16x8*)&Bs[(wn * 64 + tn * 16 + cl) * 32 + qd * 8];
#pragma unroll
        for (int tm = 0; tm < 4; ++tm)
#pragma unroll
            for (int tn = 0; tn < 4; ++tn)
                acc[tm][tn] = __builtin_amdgcn_mfma_f32_16x16x32_bf16(aF[tm], bF[tn],
                                                                      acc[tm][tn], 0, 0, 0);
        __syncthreads();
    }
    const bool f32o = (dualOut != 0) && (*flagp != 0);
    if (f32o) {
        float* Cf = (float*)Cbase + cOff;
#pragma unroll
        for (int tm = 0; tm < 4; ++tm)
#pragma unroll
            for (int tn = 0; tn < 4; ++tn)
#pragma unroll
                for (int r = 0; r < 4; ++r) {
                    const int row = rowBase + wm * 64 + tm * 16 + qd * 4 + r;
                    const int col = colBase + wn * 64 + tn * 16 + cl;
                    Cf[(size_t)row * Nd + col] = acc[tm][tn][r];
                }
    } else {
        bf16_t* Cb = (bf16_t*)Cbase + cOff;
#pragma unroll
        for (int tm = 0; tm < 4; ++tm)
#pragma unroll
            for (int tn = 0; tn < 4; ++tn)
#pragma unroll
                for (int r = 0; r < 4; ++r) {
                    const int row = rowBase + wm * 64 + tm * 16 + qd * 4 + r;
                    const int col = colBase + wn * 64 + tn * 16 + cl;
                    Cb[(size_t)row * Nd + col] = (bf16_t)acc[tm][tn][r];
                }
    }
}

// ---------------- K4: V^T per (b,h): Vt[bh][d][s] -------------------------------------
__global__ __launch_bounds__(256) void vtrans(const bf16_t* __restrict__ V,
                                              bf16_t* __restrict__ Vt) {
    __shared__ __align__(16) bf16_t T[64][72];
    const int bh = blockIdx.y, b = bh >> 4, h = bh & 15;
    const int s0 = blockIdx.x * 64;
    const int tid = threadIdx.x;
    const int rr = tid >> 3, cc8 = (tid & 7) * 8;
#pragma unroll
    for (int it = 0; it < 2; ++it) {
        const int sr = rr + it * 32;
        bf16x8 v = *(const bf16x8*)&V[((size_t)(b * S_ + s0 + sr)) * D_ + h * HD_ + cc8];
#pragma unroll
        for (int j = 0; j < 8; ++j) T[cc8 + j][sr] = v[j];
    }
    __syncthreads();
#pragma unroll
    for (int it = 0; it < 2; ++it) {
        const int dr = rr + it * 32;
        bf16x8 o;
#pragma unroll
        for (int j = 0; j < 8; ++j) o[j] = T[dr][cc8 + j];
        *(bf16x8*)&Vt[((size_t)bh * 64 + dr) * S_ + s0 + cc8] = o;
    }
}

// ---------------- K5+K6 fused: l_i pass + apply pass, LDS-staged K/V ------------------
// K chunk [32 j][64 d] staged with XOR-swizzle byte^=((row&7)<<4) (8 lanes/16B-slot on
// ds_read_b128 = optimal). V chunk [64 d][32 j] with byte^=((row&3)<<4) (also 8/slot).
// Swizzle applied on the GLOBAL SOURCE address (linear LDS dest, rule: both-sides).
__global__ __launch_bounds__(256) void attn_fused(const bf16_t* __restrict__ Q,
                                                  const bf16_t* __restrict__ Kmat,
                                                  const bf16_t* __restrict__ Vt,
                                                  const bf16_t* __restrict__ u,
                                                  void* outBase,
                                                  bf16_t* __restrict__ Xatt,
                                                  const int* flagp) {
    __shared__ __align__(16) bf16_t Ks[32 * 64];   // 4KB, swizzled rows of 128B
    __shared__ __align__(16) bf16_t Vs[64 * 32];   // 4KB, swizzled rows of 64B
    __shared__ __align__(16) bf16_t P[4][512];     // 4KB per-wave P tiles
    __shared__ __align__(16) bf16_t uS[S_];        // 2KB u row for this b
    const int bh = blockIdx.y, b = bh >> 4, h = bh & 15;
    const int tid = threadIdx.x, lane = tid & 63, wv = tid >> 6;
    const int i0 = blockIdx.x * 64 + wv * 16;
    const int qd = lane >> 4, cl = lane & 15;
    const bool f32o = (*flagp != 0);
    // attention starts at element 8388608 of d_out (element size per dtype)
    float* attF = (float*)outBase + 8388608;
    bf16_t* attB = (bf16_t*)outBase + 8388608;

    // stage u row once
    for (int t = tid; t < S_ / 8; t += 256)
        *(bf16x8*)&uS[t * 8] = *(const bf16x8*)&u[b * S_ + t * 8];

    // Q fragments held across both passes
    const bf16_t* Qb = Q + ((size_t)(b * S_ + i0 + cl)) * D_ + h * HD_ + qd * 8;
    bf16x8 aQ0 = *(const bf16x8*)Qb;
    bf16x8 aQ1 = *(const bf16x8*)(Qb + 32);

    // staging source addresses (inverse-swizzled global cols, linear LDS dest tid*16)
    const int srow_k = tid >> 3;                                   // 0..31 (j within chunk)
    const int scol_k = ((tid & 7) * 16) ^ ((srow_k & 7) << 4);     // byte within 128B row
    const bf16_t* Ksrc = Kmat + ((size_t)(b * S_) + srow_k) * D_ + h * HD_ + (scol_k >> 1);
    const int srow_v = tid >> 2;                                   // 0..63 (d)
    const int scol_v = ((tid & 3) * 16) ^ ((srow_v & 3) << 4);     // byte within 64B row
    const bf16_t* Vsrc = Vt + ((size_t)bh * 64 + srow_v) * S_ + (scol_v >> 1);

    // ---- pass 1: l_i = sum_j exp(e_ij) ----
    f32x4 l = {0.f, 0.f, 0.f, 0.f};
    for (int jb = 0; jb < S_; jb += 32) {
        gl2lds16(Ksrc + (size_t)jb * D_, (char*)Ks + tid * 16);
        __syncthreads();
#pragma unroll
        for (int js = 0; js < 2; ++js) {
            const int rj = js * 16 + cl;
            const char* kr = (const char*)Ks + rj * 128;
            const int sw = (rj & 7) << 4;
            bf16x8 k0 = *(const bf16x8*)(kr + ((qd * 16) ^ sw));
            bf16x8 k1 = *(const bf16x8*)(kr + ((64 + qd * 16) ^ sw));
            f32x4 e = {0.f, 0.f, 0.f, 0.f};
            e = __builtin_amdgcn_mfma_f32_16x16x32_bf16(aQ0, k0, e, 0, 0, 0);
            e = __builtin_amdgcn_mfma_f32_16x16x32_bf16(aQ1, k1, e, 0, 0, 0);
            l.x += __expf(clamp30(e.x));
            l.y += __expf(clamp30(e.y));
            l.z += __expf(clamp30(e.z));
            l.w += __expf(clamp30(e.w));
        }
        __syncthreads();
    }
    for (int m = 1; m < 16; m <<= 1) {
        l.x += __shfl_xor(l.x, m);
        l.y += __shfl_xor(l.y, m);
        l.z += __shfl_xor(l.z, m);
        l.w += __shfl_xor(l.w, m);
    }
    float ui[4], el[4];
    const float lv[4] = {l.x, l.y, l.z, l.w};
#pragma unroll
    for (int r = 0; r < 4; ++r) {
        ui[r] = (float)uS[i0 + qd * 4 + r];
        el[r] = fmaxf(1e-6f * lv[r], 0.f);
    }

    // ---- pass 2: attention out + P@V ----
    f32x4 accPV[4];
#pragma unroll
    for (int dt = 0; dt < 4; ++dt) accPV[dt] = (f32x4){0.f, 0.f, 0.f, 0.f};
    bf16_t* Pw = P[wv];

    for (int jb = 0; jb < S_; jb += 32) {
        gl2lds16(Ksrc + (size_t)jb * D_, (char*)Ks + tid * 16);
        gl2lds16(Vsrc + jb, (char*)Vs + tid * 16);
        __syncthreads();
#pragma unroll
        for (int js = 0; js < 2; ++js) {
            const int rj = js * 16 + cl;
            const char* kr = (const char*)Ks + rj * 128;
            const int sw = (rj & 7) << 4;
            bf16x8 k0 = *(const bf16x8*)(kr + ((qd * 16) ^ sw));
            bf16x8 k1 = *(const bf16x8*)(kr + ((64 + qd * 16) ^ sw));
            f32x4 e = {0.f, 0.f, 0.f, 0.f};
            e = __builtin_amdgcn_mfma_f32_16x16x32_bf16(aQ0, k0, e, 0, 0, 0);
            e = __builtin_amdgcn_mfma_f32_16x16x32_bf16(aQ1, k1, e, 0, 0, 0);
            const int j0 = jb + js * 16;
            const float uj = (float)uS[j0 + cl];
#pragma unroll
            for (int r = 0; r < 4; ++r) {
                float t = __expf(clamp30(e[r]));
                float num = ui[r] * uj * t;
                float att = num * __builtin_amdgcn_rcpf(el[r] + num);
                const size_t aidx = ((size_t)bh * S_ + i0 + qd * 4 + r) * S_ + j0 + cl;
                if (f32o) attF[aidx] = att;
                else attB[aidx] = (bf16_t)att;
                Pw[(qd * 4 + r) * 32 + js * 16 + cl] = (bf16_t)att;
            }
        }
        bf16x8 pA = *(const bf16x8*)&Pw[cl * 32 + qd * 8];
#pragma unroll
        for (int dt = 0; dt < 4; ++dt) {
            const int rd = dt * 16 + cl;
            const char* vr = (const char*)Vs + rd * 64;
            bf16x8 vF = *(const bf16x8*)(vr + ((qd * 16) ^ ((rd & 3) << 4)));
            accPV[dt] = __builtin_amdgcn_mfma_f32_16x16x32_bf16(pA, vF, accPV[dt], 0, 0, 0);
        }
        __syncthreads();
    }
#pragma unroll
    for (int dt = 0; dt < 4; ++dt)
#pragma unroll
        for (int r = 0; r < 4; ++r)
            Xatt[((size_t)(b * S_ + i0 + qd * 4 + r)) * D_ + h * HD_ + dt * 16 + cl] =
                (bf16_t)accPV[dt][r];
}

// ---------------- launch ---------------------------------------------------------------
extern "C" void kernel_launch(void* const* d_in, const int* in_sizes, int n_in,
                              void* d_out, int out_size, void* d_ws, size_t ws_size,
                              hipStream_t stream) {
    // ---- ws carve (~88.6 MB) ----
    float* tc      = (float*)d_ws;                    // 4096 f32
    float* biasArr = tc + 4096;                       // 4096 f32
    bf16_t* Wp     = (bf16_t*)(biasArr + 4096);       // 4M bf16
    bf16_t* QKV    = Wp + (size_t)4 * 1048576;        // 3*8M bf16
    bf16_t* Xatt   = QKV + (size_t)3 * 8388608;       // 8M bf16
    bf16_t* Vt     = Xatt + 8388608;                  // 8M bf16
    float* lsum    = (float*)(Vt + 8388608);          // 131072 f32 (unused now, keeps carve)
    bf16_t* smallC = (bf16_t*)(lsum + 131072);        // canon smalls
    bf16_t* cu     = smallC;                          // 8192
    bf16_t* ccode  = cu + 8192;                       // 512
    bf16_t* cb     = ccode + 512;                     // 1024
    bf16_t* cwcb   = cb + 1024;                       // 4*1024
    bf16_t* clng   = cwcb + 4096;                     // 4*1024
    bf16_t* clnb   = clng + 4096;                     // 4*1024
    int* flagp     = (int*)(clnb + 4096);

    // ---- big canon tensors in the dead-until-attn tail of d_out ----
    char* canonBase = (char*)d_out + 227540992;
    bf16_t* cQ   = (bf16_t*)canonBase;                // 8M
    bf16_t* cK   = cQ + 8388608;
    bf16_t* cV   = cK + 8388608;
    bf16_t* cW   = cV + 8388608;                      // 1M
    bf16_t* cwcw = cW + 1048576;                      // 4*512K

    detect_kernel<<<1, 64, 0, stream>>>((const unsigned int*)d_in[5], flagp);

    CanonArgs ca;
    const unsigned int offs[24] = {
        0u, 8388608u, 16777216u, 25165824u, 25174016u, 25174528u, 26223104u, 26224128u,
        26748416u, 26749440u, 26750464u, 26751488u,
        27275776u, 27276800u, 27277824u, 27278848u,
        27803136u, 27804160u, 27805184u, 27806208u,
        28330496u, 28331520u, 28332544u, 28333568u};
    for (int i = 0; i < 24; ++i) ca.off[i] = offs[i];
    ca.flag = flagp;
    ca.src[0] = d_in[0]; ca.dst[0] = cQ;
    ca.src[1] = d_in[1]; ca.dst[1] = cK;
    ca.src[2] = d_in[2]; ca.dst[2] = cV;
    ca.src[3] = d_in[3]; ca.dst[3] = cu;
    ca.src[4] = d_in[4]; ca.dst[4] = ccode;
    ca.src[5] = d_in[5]; ca.dst[5] = cW;
    ca.src[6] = d_in[6]; ca.dst[6] = cb;
    for (int p = 0; p < 4; ++p) {
        ca.src[7 + 4 * p]  = d_in[7 + 4 * p];  ca.dst[7 + 4 * p]  = cwcw + p * 524288;
        ca.src[8 + 4 * p]  = d_in[8 + 4 * p];  ca.dst[8 + 4 * p]  = cwcb + p * 1024;
        ca.src[9 + 4 * p]  = d_in[9 + 4 * p];  ca.dst[9 + 4 * p]  = clng + p * 1024;
        ca.src[10 + 4 * p] = d_in[10 + 4 * p]; ca.dst[10 + 4 * p] = clnb + p * 1024;
    }
    canon_kernel<<<13835, 256, 0, stream>>>(ca);

    TCArgs ta;
    ta.code = ccode;
    ta.bglob = cb;
    for (int p = 0; p < 4; ++p) {
        ta.wcw[p] = cwcw + p * 524288;
        ta.wcb[p] = cwcb + p * 1024;
        ta.lng[p] = clng + p * 1024;
        ta.lnb[p] = clnb + p * 1024;
    }
    ta.tc = tc;
    ta.biasArr = biasArr;
    tc_kernel<<<4, 256, 0, stream>>>(ta);

    wscale_kernel<<<2048, 256, 0, stream>>>(cW, tc, Wp);
    gemm_bt<<<dim3(8, 192), 256, 0, stream>>>(cQ, cK, cV, Wp, biasArr, QKV, 0, 0, flagp);
    vtrans<<<dim3(16, 128), 256, 0, stream>>>(QKV + (size_t)2 * 8388608, Vt);
    attn_fused<<<dim3(16, 128), 256, 0, stream>>>(QKV, QKV + 8388608, Vt, cu, d_out,
                                                  Xatt, flagp);
    gemm_bt<<<dim3(8, 64), 256, 0, stream>>>(Xatt, Xatt, Xatt, Wp, biasArr, d_out, 3, 1,
                                             flagp);
}

// Round 2
// 1006.498 us; speedup vs baseline: 1.0395x; 1.0395x over previous
//
#include <hip/hip_runtime.h>
#include <hip/hip_bf16.h>
#include <stdint.h>

typedef __bf16 bf16_t;
typedef __attribute__((ext_vector_type(8))) __bf16 bf16x8;
typedef __attribute__((ext_vector_type(4))) float f32x4;

#define B_  8
#define S_  1024
#define D_  1024
#define H_  16
#define HD_ 64
#define CD_ 512

typedef __attribute__((address_space(1))) const unsigned int* gas_ptr;
typedef __attribute__((address_space(3))) unsigned int* las_ptr;

__device__ __forceinline__ void gl2lds16(const void* g, void* l) {
    __builtin_amdgcn_global_load_lds((gas_ptr)(unsigned long long)g,
                                     (las_ptr)(unsigned long long)l, 16, 0, 0);
}

__device__ __forceinline__ float clamp30(float x) {
    return fminf(fmaxf(x, -30.f), 30.f);
}

// ---------------- K-1: dtype detect (0 = bf16, 1 = f32) -------------------------------
__global__ void detect_kernel(const unsigned int* Wbits, int* flag) {
    __shared__ int cnt[64];
    int c = 0;
    for (int i = threadIdx.x; i < 512; i += 64) {
        unsigned int w = Wbits[i];
        unsigned int e = (w >> 7) & 0xFFu;   // exponent field of low half-word as bf16
        c += (e >= 0x66u && e <= 0x7Fu) ? 1 : 0;
    }
    cnt[threadIdx.x] = c;
    __syncthreads();
    if (threadIdx.x == 0) {
        int t = 0;
        for (int i = 0; i < 64; ++i) t += cnt[i];
        *flag = (t >= 280) ? 0 : 1;
    }
}

// ---------------- K0: canonicalize all inputs to bf16 ---------------------------------
#define CANON_TOTAL 28333568u
struct CanonArgs {
    const void* src[23];
    bf16_t* dst[23];
    unsigned int off[24];
    const int* flag;
};

__global__ __launch_bounds__(256) void canon_kernel(CanonArgs a) {
    const bool f32 = (*a.flag != 0);
    const unsigned int e = ((unsigned int)blockIdx.x * 256u + threadIdx.x) * 8u;
    if (e >= CANON_TOTAL) return;
    int t = 0;
    while (e >= a.off[t + 1]) ++t;
    const unsigned int le = e - a.off[t];
    bf16_t* d = a.dst[t] + le;
    if (f32) {
        const float* s = (const float*)a.src[t] + le;
        bf16x8 o;
#pragma unroll
        for (int j = 0; j < 8; ++j) o[j] = (bf16_t)s[j];
        *(bf16x8*)d = o;
    } else {
        *(uint4*)d = *(const uint4*)((const bf16_t*)a.src[t] + le);
    }
}

// ---------------- K1: transformed-code vectors ----------------------------------------
struct TCArgs {
    const bf16_t* code;
    const bf16_t* bglob;
    const bf16_t* wcw[4];
    const bf16_t* wcb[4];
    const bf16_t* lng[4];
    const bf16_t* lnb[4];
    float* tc;       // [4][1024]
    float* biasArr;  // [4][1024]
};

__global__ __launch_bounds__(256) void tc_kernel(TCArgs a) {
    const int p = blockIdx.x;
    const int tid = threadIdx.x;
    __shared__ float codeS[CD_];
    __shared__ float red[256];
    __shared__ float bcast[2];
    for (int c = tid; c < CD_; c += 256) codeS[c] = (float)a.code[c];
    __syncthreads();
    float y[4];
    const bf16_t* wcw = a.wcw[p];
    for (int j = 0; j < 4; ++j) {
        const int d = tid + j * 256;
        float acc = (float)a.wcb[p][d];
        const bf16x8* row = (const bf16x8*)(wcw + (size_t)d * CD_);
        for (int c8 = 0; c8 < CD_ / 8; ++c8) {
            bf16x8 v = row[c8];
#pragma unroll
            for (int t = 0; t < 8; ++t) acc += codeS[c8 * 8 + t] * (float)v[t];
        }
        y[j] = acc;
    }
    float s = y[0] + y[1] + y[2] + y[3];
    red[tid] = s;
    __syncthreads();
    for (int off = 128; off > 0; off >>= 1) {
        if (tid < off) red[tid] += red[tid + off];
        __syncthreads();
    }
    if (tid == 0) bcast[0] = red[0] * (1.0f / (float)D_);
    __syncthreads();
    const float mu = bcast[0];
    float sq = 0.f;
    for (int j = 0; j < 4; ++j) { float t = y[j] - mu; sq += t * t; }
    red[tid] = sq;
    __syncthreads();
    for (int off = 128; off > 0; off >>= 1) {
        if (tid < off) red[tid] += red[tid + off];
        __syncthreads();
    }
    if (tid == 0) bcast[1] = red[0] * (1.0f / (float)D_);
    __syncthreads();
    const float rstd = rsqrtf(bcast[1] + 1e-5f);
    const float scale = (p == 0) ? 0.125f : 1.0f;  // fold 1/sqrt(HD) into q path
    for (int j = 0; j < 4; ++j) {
        const int d = tid + j * 256;
        float tcv = ((y[j] - mu) * rstd * (float)a.lng[p][d] + (float)a.lnb[p][d]) * scale;
        a.tc[p * D_ + d] = tcv;
        a.biasArr[p * D_ + d] = (float)a.bglob[d] * scale;
    }
}

// ---------------- K2: Wp[p][n][k] = W[n][k] * tc[p][k] --------------------------------
__global__ __launch_bounds__(256) void wscale_kernel(const bf16_t* __restrict__ W,
                                                     const float* __restrict__ tc,
                                                     bf16_t* __restrict__ Wp) {
    const size_t idx = (size_t)blockIdx.x * 256 + threadIdx.x;
    const size_t e = idx * 8;
    const int p = (int)(e >> 20);
    const size_t rem = e & 1048575;
    const int k = (int)(rem & 1023);
    bf16x8 w = *(const bf16x8*)(W + rem);
    const float* t = tc + p * 1024 + k;
    bf16x8 o;
#pragma unroll
    for (int j = 0; j < 8; ++j) o[j] = (bf16_t)((float)w[j] * t[j]);
    *(bf16x8*)(Wp + e) = o;
}

// ---------------- K3/K8: bt-GEMM  C = A @ Wp[p]^T + bias[p] ---------------------------
// XCD-chunked block swizzle (T1): the 8 col-blocks sharing an A row-panel become
// consecutive on ONE XCD instead of round-robined across all 8.
__global__ __launch_bounds__(256) void gemm_bt(const bf16_t* __restrict__ A0,
                                               const bf16_t* __restrict__ A1,
                                               const bf16_t* __restrict__ A2,
                                               const bf16_t* __restrict__ WpAll,
                                               const float* __restrict__ biasAll,
                                               void* Cbase, int pBase, int dualOut,
                                               const int* flagp) {
    constexpr int Kd = 1024, Nd = 1024;
    __shared__ __align__(16) bf16_t As[128 * 32];
    __shared__ __align__(16) bf16_t Bs[128 * 32];
    const int tid = threadIdx.x;
    // bijective chunked swizzle: nwg = 8*gridDim.y, nwg % 8 == 0 always here
    const int bid0 = blockIdx.x + 8 * blockIdx.y;
    const int bids = (bid0 & 7) * gridDim.y + (bid0 >> 3);
    const int bgx = bids & 7, bgy = bids >> 3;
    const int pl = bgy >> 6;
    const int p = pBase + pl;
    const bf16_t* A = (pl == 0) ? A0 : ((pl == 1) ? A1 : A2);
    const bf16_t* Bw = WpAll + (size_t)p * 1024 * 1024;
    const size_t cOff = (size_t)pl * 8388608;
    const int rowBase = (bgy & 63) * 128;
    const int colBase = bgx * 128;
    const int lane = tid & 63;
    const int wv = tid >> 6;
    const int wm = wv >> 1, wn = wv & 1;
    const int qd = lane >> 4, cl = lane & 15;

    f32x4 acc[4][4];
#pragma unroll
    for (int tn = 0; tn < 4; ++tn) {
        float bv = biasAll[p * 1024 + colBase + wn * 64 + tn * 16 + cl];
#pragma unroll
        for (int tm = 0; tm < 4; ++tm) acc[tm][tn] = (f32x4){bv, bv, bv, bv};
    }

    for (int kb = 0; kb < Kd; kb += 32) {
#pragma unroll
        for (int cc = 0; cc < 2; ++cc) {
            const int s = tid + cc * 256;
            const int rw = s >> 2;
            const int co = (s & 3) * 8;
            gl2lds16(A + (size_t)(rowBase + rw) * Kd + kb + co,
                     (char*)As + wv * 1024 + cc * 4096);
            gl2lds16(Bw + (size_t)(colBase + rw) * Kd + kb + co,
                     (char*)Bs + wv * 1024 + cc * 4096);
        }
        __syncthreads();
        bf16x8 aF[4], bF[4];
#pragma unroll
        for (int tm = 0; tm < 4; ++tm)
            aF[tm] = *(const bf16x8*)&As[(wm * 64 + tm * 16 + cl) * 32 + qd * 8];
#pragma unroll
        for (int tn = 0; tn < 4; ++tn)
            bF[tn] = *(const bf16x8*)&Bs[(wn * 64 + tn * 16 + cl) * 32 + qd * 8];
        __builtin_amdgcn_s_setprio(1);
#pragma unroll
        for (int tm = 0; tm < 4; ++tm)
#pragma unroll
            for (int tn = 0; tn < 4; ++tn)
                acc[tm][tn] = __builtin_amdgcn_mfma_f32_16x16x32_bf16(aF[tm], bF[tn],
                                                                      acc[tm][tn], 0, 0, 0);
        __builtin_amdgcn_s_setprio(0);
        __syncthreads();
    }
    const bool f32o = (dualOut != 0) && (*flagp != 0);
    if (f32o) {
        float* Cf = (float*)Cbase + cOff;
#pragma unroll
        for (int tm = 0; tm < 4; ++tm)
#pragma unroll
            for (int tn = 0; tn < 4; ++tn)
#pragma unroll
                for (int r = 0; r < 4; ++r) {
                    const int row = rowBase + wm * 64 + tm * 16 + qd * 4 + r;
                    const int col = colBase + wn * 64 + tn * 16 + cl;
                    Cf[(size_t)row * Nd + col] = acc[tm][tn][r];
                }
    } else {
        bf16_t* Cb = (bf16_t*)Cbase + cOff;
#pragma unroll
        for (int tm = 0; tm < 4; ++tm)
#pragma unroll
            for (int tn = 0; tn < 4; ++tn)
#pragma unroll
                for (int r = 0; r < 4; ++r) {
                    const int row = rowBase + wm * 64 + tm * 16 + qd * 4 + r;
                    const int col = colBase + wn * 64 + tn * 16 + cl;
                    Cb[(size_t)row * Nd + col] = (bf16_t)acc[tm][tn][r];
                }
    }
}

// ---------------- K4: V^T per (b,h): Vt[bh][d][s] -------------------------------------
__global__ __launch_bounds__(256) void vtrans(const bf16_t* __restrict__ V,
                                              bf16_t* __restrict__ Vt) {
    __shared__ __align__(16) bf16_t T[64][72];
    const int bh = blockIdx.y, b = bh >> 4, h = bh & 15;
    const int s0 = blockIdx.x * 64;
    const int tid = threadIdx.x;
    const int rr = tid >> 3, cc8 = (tid & 7) * 8;
#pragma unroll
    for (int it = 0; it < 2; ++it) {
        const int sr = rr + it * 32;
        bf16x8 v = *(const bf16x8*)&V[((size_t)(b * S_ + s0 + sr)) * D_ + h * HD_ + cc8];
#pragma unroll
        for (int j = 0; j < 8; ++j) T[cc8 + j][sr] = v[j];
    }
    __syncthreads();
#pragma unroll
    for (int it = 0; it < 2; ++it) {
        const int dr = rr + it * 32;
        bf16x8 o;
#pragma unroll
        for (int j = 0; j < 8; ++j) o[j] = T[dr][cc8 + j];
        *(bf16x8*)&Vt[((size_t)bh * 64 + dr) * S_ + s0 + cc8] = o;
    }
}

// ---------------- K5+K6 fused: l_i pass + apply pass, dbuf LDS-staged K/V -------------
// K chunk [32 j][64 d] staged with XOR-swizzle byte^=((row&7)<<4); V chunk [64 d][32 j]
// with byte^=((row&3)<<4). Swizzle on the GLOBAL SOURCE address (linear LDS dest).
// T3-minimum pipeline: prefetch chunk t+1 into the other buffer BEFORE computing chunk
// t; single __syncthreads per iteration (drains the prefetch after compute hid its
// latency). T1 chunked swizzle keeps one (b,h)'s K/V slice on one XCD's L2.
__global__ __launch_bounds__(256) void attn_fused(const bf16_t* __restrict__ Q,
                                                  const bf16_t* __restrict__ Kmat,
                                                  const bf16_t* __restrict__ Vt,
                                                  const bf16_t* __restrict__ u,
                                                  void* outBase,
                                                  bf16_t* __restrict__ Xatt,
                                                  const int* flagp) {
    __shared__ __align__(16) bf16_t Ks[2][32 * 64];   // 2 x 4KB
    __shared__ __align__(16) bf16_t Vs[2][64 * 32];   // 2 x 4KB
    __shared__ __align__(16) bf16_t P[4][512];        // 4KB per-wave P tiles
    __shared__ __align__(16) bf16_t uS[S_];           // 2KB u row for this b
    // bijective chunked swizzle: nwg = 2048, cpx = 256 -> XCD k owns bh in [16k,16k+16)
    const int bid0 = blockIdx.x + 16 * blockIdx.y;
    const int bids = (bid0 & 7) * 256 + (bid0 >> 3);
    const int bx = bids & 15, bh = bids >> 4;
    const int b = bh >> 4, h = bh & 15;
    const int tid = threadIdx.x, lane = tid & 63, wv = tid >> 6;
    const int i0 = bx * 64 + wv * 16;
    const int qd = lane >> 4, cl = lane & 15;
    const bool f32o = (*flagp != 0);
    // attention starts at element 8388608 of d_out (element size per dtype)
    float* attF = (float*)outBase + 8388608;
    bf16_t* attB = (bf16_t*)outBase + 8388608;

    // stage u row once
    for (int t = tid; t < S_ / 8; t += 256)
        *(bf16x8*)&uS[t * 8] = *(const bf16x8*)&u[b * S_ + t * 8];

    // Q fragments held across both passes
    const bf16_t* Qb = Q + ((size_t)(b * S_ + i0 + cl)) * D_ + h * HD_ + qd * 8;
    bf16x8 aQ0 = *(const bf16x8*)Qb;
    bf16x8 aQ1 = *(const bf16x8*)(Qb + 32);

    // staging source addresses (inverse-swizzled global cols, linear LDS dest tid*16)
    const int srow_k = tid >> 3;                                   // 0..31 (j within chunk)
    const int scol_k = ((tid & 7) * 16) ^ ((srow_k & 7) << 4);     // byte within 128B row
    const bf16_t* Ksrc = Kmat + ((size_t)(b * S_) + srow_k) * D_ + h * HD_ + (scol_k >> 1);
    const int srow_v = tid >> 2;                                   // 0..63 (d)
    const int scol_v = ((tid & 3) * 16) ^ ((srow_v & 3) << 4);     // byte within 64B row
    const bf16_t* Vsrc = Vt + ((size_t)bh * 64 + srow_v) * S_ + (scol_v >> 1);

    // ---- pass 1: l_i = sum_j exp(e_ij) ----
    gl2lds16(Ksrc, (char*)Ks[0] + tid * 16);
    __syncthreads();
    f32x4 l = {0.f, 0.f, 0.f, 0.f};
    for (int jb = 0; jb < S_; jb += 32) {
        const int cur = (jb >> 5) & 1;
        if (jb + 32 < S_)
            gl2lds16(Ksrc + (size_t)(jb + 32) * D_, (char*)Ks[cur ^ 1] + tid * 16);
#pragma unroll
        for (int js = 0; js < 2; ++js) {
            const int rj = js * 16 + cl;
            const char* kr = (const char*)Ks[cur] + rj * 128;
            const int sw = (rj & 7) << 4;
            bf16x8 k0 = *(const bf16x8*)(kr + ((qd * 16) ^ sw));
            bf16x8 k1 = *(const bf16x8*)(kr + ((64 + qd * 16) ^ sw));
            f32x4 e = {0.f, 0.f, 0.f, 0.f};
            __builtin_amdgcn_s_setprio(1);
            e = __builtin_amdgcn_mfma_f32_16x16x32_bf16(aQ0, k0, e, 0, 0, 0);
            e = __builtin_amdgcn_mfma_f32_16x16x32_bf16(aQ1, k1, e, 0, 0, 0);
            __builtin_amdgcn_s_setprio(0);
            l.x += __expf(clamp30(e.x));
            l.y += __expf(clamp30(e.y));
            l.z += __expf(clamp30(e.z));
            l.w += __expf(clamp30(e.w));
        }
        __syncthreads();
    }
    for (int m = 1; m < 16; m <<= 1) {
        l.x += __shfl_xor(l.x, m);
        l.y += __shfl_xor(l.y, m);
        l.z += __shfl_xor(l.z, m);
        l.w += __shfl_xor(l.w, m);
    }
    float ui[4], el[4];
    const float lv[4] = {l.x, l.y, l.z, l.w};
#pragma unroll
    for (int r = 0; r < 4; ++r) {
        ui[r] = (float)uS[i0 + qd * 4 + r];
        el[r] = fmaxf(1e-6f * lv[r], 0.f);
    }

    // ---- pass 2: attention out + P@V ----
    f32x4 accPV[4];
#pragma unroll
    for (int dt = 0; dt < 4; ++dt) accPV[dt] = (f32x4){0.f, 0.f, 0.f, 0.f};
    bf16_t* Pw = P[wv];

    gl2lds16(Ksrc, (char*)Ks[0] + tid * 16);
    gl2lds16(Vsrc, (char*)Vs[0] + tid * 16);
    __syncthreads();
    for (int jb = 0; jb < S_; jb += 32) {
        const int cur = (jb >> 5) & 1;
        if (jb + 32 < S_) {
            gl2lds16(Ksrc + (size_t)(jb + 32) * D_, (char*)Ks[cur ^ 1] + tid * 16);
            gl2lds16(Vsrc + (jb + 32), (char*)Vs[cur ^ 1] + tid * 16);
        }
#pragma unroll
        for (int js = 0; js < 2; ++js) {
            const int rj = js * 16 + cl;
            const char* kr = (const char*)Ks[cur] + rj * 128;
            const int sw = (rj & 7) << 4;
            bf16x8 k0 = *(const bf16x8*)(kr + ((qd * 16) ^ sw));
            bf16x8 k1 = *(const bf16x8*)(kr + ((64 + qd * 16) ^ sw));
            f32x4 e = {0.f, 0.f, 0.f, 0.f};
            __builtin_amdgcn_s_setprio(1);
            e = __builtin_amdgcn_mfma_f32_16x16x32_bf16(aQ0, k0, e, 0, 0, 0);
            e = __builtin_amdgcn_mfma_f32_16x16x32_bf16(aQ1, k1, e, 0, 0, 0);
            __builtin_amdgcn_s_setprio(0);
            const int j0 = jb + js * 16;
            const float uj = (float)uS[j0 + cl];
#pragma unroll
            for (int r = 0; r < 4; ++r) {
                float t = __expf(clamp30(e[r]));
                float num = ui[r] * uj * t;
                float att = num * __builtin_amdgcn_rcpf(el[r] + num);
                const size_t aidx = ((size_t)bh * S_ + i0 + qd * 4 + r) * S_ + j0 + cl;
                if (f32o) attF[aidx] = att;
                else attB[aidx] = (bf16_t)att;
                Pw[(qd * 4 + r) * 32 + js * 16 + cl] = (bf16_t)att;
            }
        }
        bf16x8 pA = *(const bf16x8*)&Pw[cl * 32 + qd * 8];
        __builtin_amdgcn_s_setprio(1);
#pragma unroll
        for (int dt = 0; dt < 4; ++dt) {
            const int rd = dt * 16 + cl;
            const char* vr = (const char*)Vs[cur] + rd * 64;
            bf16x8 vF = *(const bf16x8*)(vr + ((qd * 16) ^ ((rd & 3) << 4)));
            accPV[dt] = __builtin_amdgcn_mfma_f32_16x16x32_bf16(pA, vF, accPV[dt], 0, 0, 0);
        }
        __builtin_amdgcn_s_setprio(0);
        __syncthreads();
    }
#pragma unroll
    for (int dt = 0; dt < 4; ++dt)
#pragma unroll
        for (int r = 0; r < 4; ++r)
            Xatt[((size_t)(b * S_ + i0 + qd * 4 + r)) * D_ + h * HD_ + dt * 16 + cl] =
                (bf16_t)accPV[dt][r];
}

// ---------------- launch ---------------------------------------------------------------
extern "C" void kernel_launch(void* const* d_in, const int* in_sizes, int n_in,
                              void* d_out, int out_size, void* d_ws, size_t ws_size,
                              hipStream_t stream) {
    // ---- ws carve (~88.6 MB) ----
    float* tc      = (float*)d_ws;                    // 4096 f32
    float* biasArr = tc + 4096;                       // 4096 f32
    bf16_t* Wp     = (bf16_t*)(biasArr + 4096);       // 4M bf16
    bf16_t* QKV    = Wp + (size_t)4 * 1048576;        // 3*8M bf16
    bf16_t* Xatt   = QKV + (size_t)3 * 8388608;       // 8M bf16
    bf16_t* Vt     = Xatt + 8388608;                  // 8M bf16
    float* lsum    = (float*)(Vt + 8388608);          // 131072 f32 (unused now, keeps carve)
    bf16_t* smallC = (bf16_t*)(lsum + 131072);        // canon smalls
    bf16_t* cu     = smallC;                          // 8192
    bf16_t* ccode  = cu + 8192;                       // 512
    bf16_t* cb     = ccode + 512;                     // 1024
    bf16_t* cwcb   = cb + 1024;                       // 4*1024
    bf16_t* clng   = cwcb + 4096;                     // 4*1024
    bf16_t* clnb   = clng + 4096;                     // 4*1024
    int* flagp     = (int*)(clnb + 4096);

    // ---- big canon tensors in the dead-until-attn tail of d_out ----
    char* canonBase = (char*)d_out + 227540992;
    bf16_t* cQ   = (bf16_t*)canonBase;                // 8M
    bf16_t* cK   = cQ + 8388608;
    bf16_t* cV   = cK + 8388608;
    bf16_t* cW   = cV + 8388608;                      // 1M
    bf16_t* cwcw = cW + 1048576;                      // 4*512K

    detect_kernel<<<1, 64, 0, stream>>>((const unsigned int*)d_in[5], flagp);

    CanonArgs ca;
    const unsigned int offs[24] = {
        0u, 8388608u, 16777216u, 25165824u, 25174016u, 25174528u, 26223104u, 26224128u,
        26748416u, 26749440u, 26750464u, 26751488u,
        27275776u, 27276800u, 27277824u, 27278848u,
        27803136u, 27804160u, 27805184u, 27806208u,
        28330496u, 28331520u, 28332544u, 28333568u};
    for (int i = 0; i < 24; ++i) ca.off[i] = offs[i];
    ca.flag = flagp;
    ca.src[0] = d_in[0]; ca.dst[0] = cQ;
    ca.src[1] = d_in[1]; ca.dst[1] = cK;
    ca.src[2] = d_in[2]; ca.dst[2] = cV;
    ca.src[3] = d_in[3]; ca.dst[3] = cu;
    ca.src[4] = d_in[4]; ca.dst[4] = ccode;
    ca.src[5] = d_in[5]; ca.dst[5] = cW;
    ca.src[6] = d_in[6]; ca.dst[6] = cb;
    for (int p = 0; p < 4; ++p) {
        ca.src[7 + 4 * p]  = d_in[7 + 4 * p];  ca.dst[7 + 4 * p]  = cwcw + p * 524288;
        ca.src[8 + 4 * p]  = d_in[8 + 4 * p];  ca.dst[8 + 4 * p]  = cwcb + p * 1024;
        ca.src[9 + 4 * p]  = d_in[9 + 4 * p];  ca.dst[9 + 4 * p]  = clng + p * 1024;
        ca.src[10 + 4 * p] = d_in[10 + 4 * p]; ca.dst[10 + 4 * p] = clnb + p * 1024;
    }
    canon_kernel<<<13835, 256, 0, stream>>>(ca);

    TCArgs ta;
    ta.code = ccode;
    ta.bglob = cb;
    for (int p = 0; p < 4; ++p) {
        ta.wcw[p] = cwcw + p * 524288;
        ta.wcb[p] = cwcb + p * 1024;
        ta.lng[p] = clng + p * 1024;
        ta.lnb[p] = clnb + p * 1024;
    }
    ta.tc = tc;
    ta.biasArr = biasArr;
    tc_kernel<<<4, 256, 0, stream>>>(ta);

    wscale_kernel<<<2048, 256, 0, stream>>>(cW, tc, Wp);
    gemm_bt<<<dim3(8, 192), 256, 0, stream>>>(cQ, cK, cV, Wp, biasArr, QKV, 0, 0, flagp);
    vtrans<<<dim3(16, 128), 256, 0, stream>>>(QKV + (size_t)2 * 8388608, Vt);
    attn_fused<<<dim3(16, 128), 256, 0, stream>>>(QKV, QKV + 8388608, Vt, cu, d_out,
                                                  Xatt, flagp);
    gemm_bt<<<dim3(8, 64), 256, 0, stream>>>(Xatt, Xatt, Xatt, Wp, biasArr, d_out, 3, 1,
                                             flagp);
}

// Round 3
// 946.026 us; speedup vs baseline: 1.1059x; 1.0639x over previous
//
#include <hip/hip_runtime.h>
#include <hip/hip_bf16.h>
#include <stdint.h>

typedef __bf16 bf16_t;
typedef __attribute__((ext_vector_type(8))) __bf16 bf16x8;
typedef __attribute__((ext_vector_type(4))) float f32x4;

#define B_  8
#define S_  1024
#define D_  1024
#define H_  16
#define HD_ 64
#define CD_ 512

typedef __attribute__((address_space(1))) const unsigned int* gas_ptr;
typedef __attribute__((address_space(3))) unsigned int* las_ptr;

__device__ __forceinline__ void gl2lds16(const void* g, void* l) {
    __builtin_amdgcn_global_load_lds((gas_ptr)(unsigned long long)g,
                                     (las_ptr)(unsigned long long)l, 16, 0, 0);
}

__device__ __forceinline__ float clamp30(float x) {
    return fminf(fmaxf(x, -30.f), 30.f);
}

// ---------------- K0: canonicalize all inputs to bf16 + self-computed dtype flag ------
// flag (0 = bf16, 1 = f32) is derived per-block from W's first 512 dwords (identical
// arithmetic to the old detect_kernel); block 0 publishes it for attn/gemm2.
#define CANON_TOTAL 28333568u
struct CanonArgs {
    const void* src[23];
    bf16_t* dst[23];
    unsigned int off[24];
    int* flagOut;
};

__global__ __launch_bounds__(256) void canon_kernel(CanonArgs a) {
    __shared__ int flagS;
    const int tid = threadIdx.x;
    if (tid < 64) {
        int c = 0;
        const unsigned int* wb = (const unsigned int*)a.src[5];
        for (int i = tid; i < 512; i += 64) {
            unsigned int w = wb[i];
            unsigned int ex = (w >> 7) & 0xFFu;
            c += (ex >= 0x66u && ex <= 0x7Fu) ? 1 : 0;
        }
        for (int m = 1; m < 64; m <<= 1) c += __shfl_xor(c, m);
        if (tid == 0) flagS = (c >= 280) ? 0 : 1;
    }
    __syncthreads();
    const bool f32 = (flagS != 0);
    if (blockIdx.x == 0 && tid == 0) *a.flagOut = flagS;

    const unsigned int e = ((unsigned int)blockIdx.x * 256u + tid) * 8u;
    if (e >= CANON_TOTAL) return;
    int t = 0;
    while (e >= a.off[t + 1]) ++t;
    const unsigned int le = e - a.off[t];
    bf16_t* d = a.dst[t] + le;
    if (f32) {
        const float* s = (const float*)a.src[t] + le;
        bf16x8 o;
#pragma unroll
        for (int j = 0; j < 8; ++j) o[j] = (bf16_t)s[j];
        *(bf16x8*)d = o;
    } else {
        *(uint4*)d = *(const uint4*)((const bf16_t*)a.src[t] + le);
    }
}

// ---------------- K1: transformed-code vectors ----------------------------------------
struct TCArgs {
    const bf16_t* code;
    const bf16_t* bglob;
    const bf16_t* wcw[4];
    const bf16_t* wcb[4];
    const bf16_t* lng[4];
    const bf16_t* lnb[4];
    float* tc;       // [4][1024]
    float* biasArr;  // [4][1024]
};

__global__ __launch_bounds__(512) void tc_kernel(TCArgs a) {
    const int p = blockIdx.x;
    const int tid = threadIdx.x;
    __shared__ float codeS[CD_];
    __shared__ float red[512];
    __shared__ float bcast[2];
    for (int c = tid; c < CD_; c += 512) codeS[c] = (float)a.code[c];
    __syncthreads();
    float y[2];
    const bf16_t* wcw = a.wcw[p];
    for (int j = 0; j < 2; ++j) {
        const int d = tid + j * 512;
        float acc = (float)a.wcb[p][d];
        const bf16x8* row = (const bf16x8*)(wcw + (size_t)d * CD_);
        for (int c8 = 0; c8 < CD_ / 8; ++c8) {
            bf16x8 v = row[c8];
#pragma unroll
            for (int t = 0; t < 8; ++t) acc += codeS[c8 * 8 + t] * (float)v[t];
        }
        y[j] = acc;
    }
    red[tid] = y[0] + y[1];
    __syncthreads();
    for (int off = 256; off > 0; off >>= 1) {
        if (tid < off) red[tid] += red[tid + off];
        __syncthreads();
    }
    if (tid == 0) bcast[0] = red[0] * (1.0f / (float)D_);
    __syncthreads();
    const float mu = bcast[0];
    float sq = 0.f;
    for (int j = 0; j < 2; ++j) { float t = y[j] - mu; sq += t * t; }
    red[tid] = sq;
    __syncthreads();
    for (int off = 256; off > 0; off >>= 1) {
        if (tid < off) red[tid] += red[tid + off];
        __syncthreads();
    }
    if (tid == 0) bcast[1] = red[0] * (1.0f / (float)D_);
    __syncthreads();
    const float rstd = rsqrtf(bcast[1] + 1e-5f);
    const float scale = (p == 0) ? 0.125f : 1.0f;  // fold 1/sqrt(HD) into q path
    for (int j = 0; j < 2; ++j) {
        const int d = tid + j * 512;
        float tcv = ((y[j] - mu) * rstd * (float)a.lng[p][d] + (float)a.lnb[p][d]) * scale;
        a.tc[p * D_ + d] = tcv;
        a.biasArr[p * D_ + d] = (float)a.bglob[d] * scale;
    }
}

// ---------------- K2: Wp[p][n][k] = W[n][k] * tc[p][k] --------------------------------
__global__ __launch_bounds__(256) void wscale_kernel(const bf16_t* __restrict__ W,
                                                     const float* __restrict__ tc,
                                                     bf16_t* __restrict__ Wp) {
    const size_t idx = (size_t)blockIdx.x * 256 + threadIdx.x;
    const size_t e = idx * 8;
    const int p = (int)(e >> 20);
    const size_t rem = e & 1048575;
    const int k = (int)(rem & 1023);
    bf16x8 w = *(const bf16x8*)(W + rem);
    const float* t = tc + p * 1024 + k;
    bf16x8 o;
#pragma unroll
    for (int j = 0; j < 8; ++j) o[j] = (bf16_t)((float)w[j] * t[j]);
    *(bf16x8*)(Wp + e) = o;
}

// ---------------- K3/K8: bt-GEMM  C = A @ Wp[p]^T + bias[p] ---------------------------
// XCD-chunked block swizzle (T1) + T3-minimum 2-phase: double-buffered LDS, prefetch
// K-step t+1 issued BEFORE the MFMAs of step t, one barrier per K-step (the barrier's
// vmcnt(0) drain lands after ~180 cy of ds_read+MFMA has hidden most of the L2 latency).
__global__ __launch_bounds__(256) void gemm_bt(const bf16_t* __restrict__ A0,
                                               const bf16_t* __restrict__ A1,
                                               const bf16_t* __restrict__ A2,
                                               const bf16_t* __restrict__ WpAll,
                                               const float* __restrict__ biasAll,
                                               void* Cbase, int pBase, int dualOut,
                                               const int* flagp) {
    constexpr int Kd = 1024, Nd = 1024;
    __shared__ __align__(16) bf16_t As[2][128 * 32];
    __shared__ __align__(16) bf16_t Bs[2][128 * 32];
    const int tid = threadIdx.x;
    // bijective chunked swizzle: nwg = 8*gridDim.y, nwg % 8 == 0 always here
    const int bid0 = blockIdx.x + 8 * blockIdx.y;
    const int bids = (bid0 & 7) * gridDim.y + (bid0 >> 3);
    const int bgx = bids & 7, bgy = bids >> 3;
    const int pl = bgy >> 6;
    const int p = pBase + pl;
    const bf16_t* A = (pl == 0) ? A0 : ((pl == 1) ? A1 : A2);
    const bf16_t* Bw = WpAll + (size_t)p * 1024 * 1024;
    const size_t cOff = (size_t)pl * 8388608;
    const int rowBase = (bgy & 63) * 128;
    const int colBase = bgx * 128;
    const int lane = tid & 63;
    const int wv = tid >> 6;
    const int wm = wv >> 1, wn = wv & 1;
    const int qd = lane >> 4, cl = lane & 15;

    // per-thread staging geometry (two 16B chunks each for A and B)
    const int rw0 = tid >> 2, rw1 = (tid + 256) >> 2;
    const int co0 = (tid & 3) * 8, co1 = ((tid + 256) & 3) * 8;
    const bf16_t* Asrc0 = A + (size_t)(rowBase + rw0) * Kd + co0;
    const bf16_t* Asrc1 = A + (size_t)(rowBase + rw1) * Kd + co1;
    const bf16_t* Bsrc0 = Bw + (size_t)(colBase + rw0) * Kd + co0;
    const bf16_t* Bsrc1 = Bw + (size_t)(colBase + rw1) * Kd + co1;
    const int ldst0 = wv * 1024 + (tid & 63) * 16;          // == tid*16 within 8KB buf
    // NOTE: LDS dest for chunk cc is (tid + cc*256)*16 bytes within the 8 KB buffer.

    f32x4 acc[4][4];
#pragma unroll
    for (int tn = 0; tn < 4; ++tn) {
        float bv = biasAll[p * 1024 + colBase + wn * 64 + tn * 16 + cl];
#pragma unroll
        for (int tm = 0; tm < 4; ++tm) acc[tm][tn] = (f32x4){bv, bv, bv, bv};
    }
    (void)ldst0;

    // prologue: stage kb=0 into buffer 0
    {
        gl2lds16(Asrc0, (char*)As[0] + (size_t)tid * 16);
        gl2lds16(Asrc1, (char*)As[0] + (size_t)(tid + 256) * 16);
        gl2lds16(Bsrc0, (char*)Bs[0] + (size_t)tid * 16);
        gl2lds16(Bsrc1, (char*)Bs[0] + (size_t)(tid + 256) * 16);
    }
    __syncthreads();

    for (int kb = 0; kb < Kd; kb += 32) {
        const int cur = (kb >> 5) & 1;
        if (kb + 32 < Kd) {
            const int nk = kb + 32;
            gl2lds16(Asrc0 + nk, (char*)As[cur ^ 1] + (size_t)tid * 16);
            gl2lds16(Asrc1 + nk, (char*)As[cur ^ 1] + (size_t)(tid + 256) * 16);
            gl2lds16(Bsrc0 + nk, (char*)Bs[cur ^ 1] + (size_t)tid * 16);
            gl2lds16(Bsrc1 + nk, (char*)Bs[cur ^ 1] + (size_t)(tid + 256) * 16);
        }
        bf16x8 aF[4], bF[4];
#pragma unroll
        for (int tm = 0; tm < 4; ++tm)
            aF[tm] = *(const bf16x8*)&As[cur][(wm * 64 + tm * 16 + cl) * 32 + qd * 8];
#pragma unroll
        for (int tn = 0; tn < 4; ++tn)
            bF[tn] = *(const bf16x8*)&Bs[cur][(wn * 64 + tn * 16 + cl) * 32 + qd * 8];
        __builtin_amdgcn_s_setprio(1);
#pragma unroll
        for (int tm = 0; tm < 4; ++tm)
#pragma unroll
            for (int tn = 0; tn < 4; ++tn)
                acc[tm][tn] = __builtin_amdgcn_mfma_f32_16x16x32_bf16(aF[tm], bF[tn],
                                                                      acc[tm][tn], 0, 0, 0);
        __builtin_amdgcn_s_setprio(0);
        __syncthreads();
    }
    const bool f32o = (dualOut != 0) && (*flagp != 0);
    if (f32o) {
        float* Cf = (float*)Cbase + cOff;
#pragma unroll
        for (int tm = 0; tm < 4; ++tm)
#pragma unroll
            for (int tn = 0; tn < 4; ++tn)
#pragma unroll
                for (int r = 0; r < 4; ++r) {
                    const int row = rowBase + wm * 64 + tm * 16 + qd * 4 + r;
                    const int col = colBase + wn * 64 + tn * 16 + cl;
                    Cf[(size_t)row * Nd + col] = acc[tm][tn][r];
                }
    } else {
        bf16_t* Cb = (bf16_t*)Cbase + cOff;
#pragma unroll
        for (int tm = 0; tm < 4; ++tm)
#pragma unroll
            for (int tn = 0; tn < 4; ++tn)
#pragma unroll
                for (int r = 0; r < 4; ++r) {
                    const int row = rowBase + wm * 64 + tm * 16 + qd * 4 + r;
                    const int col = colBase + wn * 64 + tn * 16 + cl;
                    Cb[(size_t)row * Nd + col] = (bf16_t)acc[tm][tn][r];
                }
    }
}

// ---------------- K4: V^T per (b,h): Vt[bh][d][s] -------------------------------------
__global__ __launch_bounds__(256) void vtrans(const bf16_t* __restrict__ V,
                                              bf16_t* __restrict__ Vt) {
    __shared__ __align__(16) bf16_t T[64][72];
    const int bh = blockIdx.y, b = bh >> 4, h = bh & 15;
    const int s0 = blockIdx.x * 64;
    const int tid = threadIdx.x;
    const int rr = tid >> 3, cc8 = (tid & 7) * 8;
#pragma unroll
    for (int it = 0; it < 2; ++it) {
        const int sr = rr + it * 32;
        bf16x8 v = *(const bf16x8*)&V[((size_t)(b * S_ + s0 + sr)) * D_ + h * HD_ + cc8];
#pragma unroll
        for (int j = 0; j < 8; ++j) T[cc8 + j][sr] = v[j];
    }
    __syncthreads();
#pragma unroll
    for (int it = 0; it < 2; ++it) {
        const int dr = rr + it * 32;
        bf16x8 o;
#pragma unroll
        for (int j = 0; j < 8; ++j) o[j] = T[dr][cc8 + j];
        *(bf16x8*)&Vt[((size_t)bh * 64 + dr) * S_ + s0 + cc8] = o;
    }
}

// ---------------- K5+K6 fused: l_i pass + apply pass, dbuf LDS-staged K/V -------------
// K chunk [32 j][64 d] staged with XOR-swizzle byte^=((row&7)<<4); V chunk [64 d][32 j]
// with byte^=((row&3)<<4). Swizzle on the GLOBAL SOURCE address (linear LDS dest).
// T3-minimum pipeline + T1 chunked swizzle (one (b,h)'s K/V slice stays on one XCD L2).
__global__ __launch_bounds__(256) void attn_fused(const bf16_t* __restrict__ Q,
                                                  const bf16_t* __restrict__ Kmat,
                                                  const bf16_t* __restrict__ Vt,
                                                  const bf16_t* __restrict__ u,
                                                  void* outBase,
                                                  bf16_t* __restrict__ Xatt,
                                                  const int* flagp) {
    __shared__ __align__(16) bf16_t Ks[2][32 * 64];   // 2 x 4KB
    __shared__ __align__(16) bf16_t Vs[2][64 * 32];   // 2 x 4KB
    __shared__ __align__(16) bf16_t P[4][512];        // 4KB per-wave P tiles
    __shared__ __align__(16) bf16_t uS[S_];           // 2KB u row for this b
    // bijective chunked swizzle: nwg = 2048, cpx = 256 -> XCD k owns bh in [16k,16k+16)
    const int bid0 = blockIdx.x + 16 * blockIdx.y;
    const int bids = (bid0 & 7) * 256 + (bid0 >> 3);
    const int bx = bids & 15, bh = bids >> 4;
    const int b = bh >> 4, h = bh & 15;
    const int tid = threadIdx.x, lane = tid & 63, wv = tid >> 6;
    const int i0 = bx * 64 + wv * 16;
    const int qd = lane >> 4, cl = lane & 15;
    const bool f32o = (*flagp != 0);
    // attention starts at element 8388608 of d_out (element size per dtype)
    float* attF = (float*)outBase + 8388608;
    bf16_t* attB = (bf16_t*)outBase + 8388608;

    // stage u row once
    for (int t = tid; t < S_ / 8; t += 256)
        *(bf16x8*)&uS[t * 8] = *(const bf16x8*)&u[b * S_ + t * 8];

    // Q fragments held across both passes
    const bf16_t* Qb = Q + ((size_t)(b * S_ + i0 + cl)) * D_ + h * HD_ + qd * 8;
    bf16x8 aQ0 = *(const bf16x8*)Qb;
    bf16x8 aQ1 = *(const bf16x8*)(Qb + 32);

    // staging source addresses (inverse-swizzled global cols, linear LDS dest tid*16)
    const int srow_k = tid >> 3;                                   // 0..31 (j within chunk)
    const int scol_k = ((tid & 7) * 16) ^ ((srow_k & 7) << 4);     // byte within 128B row
    const bf16_t* Ksrc = Kmat + ((size_t)(b * S_) + srow_k) * D_ + h * HD_ + (scol_k >> 1);
    const int srow_v = tid >> 2;                                   // 0..63 (d)
    const int scol_v = ((tid & 3) * 16) ^ ((srow_v & 3) << 4);     // byte within 64B row
    const bf16_t* Vsrc = Vt + ((size_t)bh * 64 + srow_v) * S_ + (scol_v >> 1);

    // ---- pass 1: l_i = sum_j exp(e_ij) ----
    gl2lds16(Ksrc, (char*)Ks[0] + tid * 16);
    __syncthreads();
    f32x4 l = {0.f, 0.f, 0.f, 0.f};
    for (int jb = 0; jb < S_; jb += 32) {
        const int cur = (jb >> 5) & 1;
        if (jb + 32 < S_)
            gl2lds16(Ksrc + (size_t)(jb + 32) * D_, (char*)Ks[cur ^ 1] + tid * 16);
#pragma unroll
        for (int js = 0; js < 2; ++js) {
            const int rj = js * 16 + cl;
            const char* kr = (const char*)Ks[cur] + rj * 128;
            const int sw = (rj & 7) << 4;
            bf16x8 k0 = *(const bf16x8*)(kr + ((qd * 16) ^ sw));
            bf16x8 k1 = *(const bf16x8*)(kr + ((64 + qd * 16) ^ sw));
            f32x4 e = {0.f, 0.f, 0.f, 0.f};
            __builtin_amdgcn_s_setprio(1);
            e = __builtin_amdgcn_mfma_f32_16x16x32_bf16(aQ0, k0, e, 0, 0, 0);
            e = __builtin_amdgcn_mfma_f32_16x16x32_bf16(aQ1, k1, e, 0, 0, 0);
            __builtin_amdgcn_s_setprio(0);
            l.x += __expf(clamp30(e.x));
            l.y += __expf(clamp30(e.y));
            l.z += __expf(clamp30(e.z));
            l.w += __expf(clamp30(e.w));
        }
        __syncthreads();
    }
    for (int m = 1; m < 16; m <<= 1) {
        l.x += __shfl_xor(l.x, m);
        l.y += __shfl_xor(l.y, m);
        l.z += __shfl_xor(l.z, m);
        l.w += __shfl_xor(l.w, m);
    }
    float ui[4], el[4];
    const float lv[4] = {l.x, l.y, l.z, l.w};
#pragma unroll
    for (int r = 0; r < 4; ++r) {
        ui[r] = (float)uS[i0 + qd * 4 + r];
        el[r] = fmaxf(1e-6f * lv[r], 0.f);
    }

    // ---- pass 2: attention out + P@V ----
    f32x4 accPV[4];
#pragma unroll
    for (int dt = 0; dt < 4; ++dt) accPV[dt] = (f32x4){0.f, 0.f, 0.f, 0.f};
    bf16_t* Pw = P[wv];

    gl2lds16(Ksrc, (char*)Ks[0] + tid * 16);
    gl2lds16(Vsrc, (char*)Vs[0] + tid * 16);
    __syncthreads();
    for (int jb = 0; jb < S_; jb += 32) {
        const int cur = (jb >> 5) & 1;
        if (jb + 32 < S_) {
            gl2lds16(Ksrc + (size_t)(jb + 32) * D_, (char*)Ks[cur ^ 1] + tid * 16);
            gl2lds16(Vsrc + (jb + 32), (char*)Vs[cur ^ 1] + tid * 16);
        }
#pragma unroll
        for (int js = 0; js < 2; ++js) {
            const int rj = js * 16 + cl;
            const char* kr = (const char*)Ks[cur] + rj * 128;
            const int sw = (rj & 7) << 4;
            bf16x8 k0 = *(const bf16x8*)(kr + ((qd * 16) ^ sw));
            bf16x8 k1 = *(const bf16x8*)(kr + ((64 + qd * 16) ^ sw));
            f32x4 e = {0.f, 0.f, 0.f, 0.f};
            __builtin_amdgcn_s_setprio(1);
            e = __builtin_amdgcn_mfma_f32_16x16x32_bf16(aQ0, k0, e, 0, 0, 0);
            e = __builtin_amdgcn_mfma_f32_16x16x32_bf16(aQ1, k1, e, 0, 0, 0);
            __builtin_amdgcn_s_setprio(0);
            const int j0 = jb + js * 16;
            const float uj = (float)uS[j0 + cl];
#pragma unroll
            for (int r = 0; r < 4; ++r) {
                float t = __expf(clamp30(e[r]));
                float num = ui[r] * uj * t;
                float att = num * __builtin_amdgcn_rcpf(el[r] + num);
                const size_t aidx = ((size_t)bh * S_ + i0 + qd * 4 + r) * S_ + j0 + cl;
                if (f32o) attF[aidx] = att;
                else attB[aidx] = (bf16_t)att;
                Pw[(qd * 4 + r) * 32 + js * 16 + cl] = (bf16_t)att;
            }
        }
        bf16x8 pA = *(const bf16x8*)&Pw[cl * 32 + qd * 8];
        __builtin_amdgcn_s_setprio(1);
#pragma unroll
        for (int dt = 0; dt < 4; ++dt) {
            const int rd = dt * 16 + cl;
            const char* vr = (const char*)Vs[cur] + rd * 64;
            bf16x8 vF = *(const bf16x8*)(vr + ((qd * 16) ^ ((rd & 3) << 4)));
            accPV[dt] = __builtin_amdgcn_mfma_f32_16x16x32_bf16(pA, vF, accPV[dt], 0, 0, 0);
        }
        __builtin_amdgcn_s_setprio(0);
        __syncthreads();
    }
#pragma unroll
    for (int dt = 0; dt < 4; ++dt)
#pragma unroll
        for (int r = 0; r < 4; ++r)
            Xatt[((size_t)(b * S_ + i0 + qd * 4 + r)) * D_ + h * HD_ + dt * 16 + cl] =
                (bf16_t)accPV[dt][r];
}

// ---------------- launch ---------------------------------------------------------------
extern "C" void kernel_launch(void* const* d_in, const int* in_sizes, int n_in,
                              void* d_out, int out_size, void* d_ws, size_t ws_size,
                              hipStream_t stream) {
    // ---- ws carve (~88.6 MB) ----
    float* tc      = (float*)d_ws;                    // 4096 f32
    float* biasArr = tc + 4096;                       // 4096 f32
    bf16_t* Wp     = (bf16_t*)(biasArr + 4096);       // 4M bf16
    bf16_t* QKV    = Wp + (size_t)4 * 1048576;        // 3*8M bf16
    bf16_t* Xatt   = QKV + (size_t)3 * 8388608;       // 8M bf16
    bf16_t* Vt     = Xatt + 8388608;                  // 8M bf16
    float* lsum    = (float*)(Vt + 8388608);          // 131072 f32 (unused, keeps carve)
    bf16_t* smallC = (bf16_t*)(lsum + 131072);        // canon smalls
    bf16_t* cu     = smallC;                          // 8192
    bf16_t* ccode  = cu + 8192;                       // 512
    bf16_t* cb     = ccode + 512;                     // 1024
    bf16_t* cwcb   = cb + 1024;                       // 4*1024
    bf16_t* clng   = cwcb + 4096;                     // 4*1024
    bf16_t* clnb   = clng + 4096;                     // 4*1024
    int* flagp     = (int*)(clnb + 4096);

    // ---- big canon tensors in the dead-until-attn tail of d_out ----
    char* canonBase = (char*)d_out + 227540992;
    bf16_t* cQ   = (bf16_t*)canonBase;                // 8M
    bf16_t* cK   = cQ + 8388608;
    bf16_t* cV   = cK + 8388608;
    bf16_t* cW   = cV + 8388608;                      // 1M
    bf16_t* cwcw = cW + 1048576;                      // 4*512K

    CanonArgs ca;
    const unsigned int offs[24] = {
        0u, 8388608u, 16777216u, 25165824u, 25174016u, 25174528u, 26223104u, 26224128u,
        26748416u, 26749440u, 26750464u, 26751488u,
        27275776u, 27276800u, 27277824u, 27278848u,
        27803136u, 27804160u, 27805184u, 27806208u,
        28330496u, 28331520u, 28332544u, 28333568u};
    for (int i = 0; i < 24; ++i) ca.off[i] = offs[i];
    ca.flagOut = flagp;
    ca.src[0] = d_in[0]; ca.dst[0] = cQ;
    ca.src[1] = d_in[1]; ca.dst[1] = cK;
    ca.src[2] = d_in[2]; ca.dst[2] = cV;
    ca.src[3] = d_in[3]; ca.dst[3] = cu;
    ca.src[4] = d_in[4]; ca.dst[4] = ccode;
    ca.src[5] = d_in[5]; ca.dst[5] = cW;
    ca.src[6] = d_in[6]; ca.dst[6] = cb;
    for (int p = 0; p < 4; ++p) {
        ca.src[7 + 4 * p]  = d_in[7 + 4 * p];  ca.dst[7 + 4 * p]  = cwcw + p * 524288;
        ca.src[8 + 4 * p]  = d_in[8 + 4 * p];  ca.dst[8 + 4 * p]  = cwcb + p * 1024;
        ca.src[9 + 4 * p]  = d_in[9 + 4 * p];  ca.dst[9 + 4 * p]  = clng + p * 1024;
        ca.src[10 + 4 * p] = d_in[10 + 4 * p]; ca.dst[10 + 4 * p] = clnb + p * 1024;
    }
    canon_kernel<<<13835, 256, 0, stream>>>(ca);

    TCArgs ta;
    ta.code = ccode;
    ta.bglob = cb;
    for (int p = 0; p < 4; ++p) {
        ta.wcw[p] = cwcw + p * 524288;
        ta.wcb[p] = cwcb + p * 1024;
        ta.lng[p] = clng + p * 1024;
        ta.lnb[p] = clnb + p * 1024;
    }
    ta.tc = tc;
    ta.biasArr = biasArr;
    tc_kernel<<<4, 512, 0, stream>>>(ta);

    wscale_kernel<<<2048, 256, 0, stream>>>(cW, tc, Wp);
    gemm_bt<<<dim3(8, 192), 256, 0, stream>>>(cQ, cK, cV, Wp, biasArr, QKV, 0, 0, flagp);
    vtrans<<<dim3(16, 128), 256, 0, stream>>>(QKV + (size_t)2 * 8388608, Vt);
    attn_fused<<<dim3(16, 128), 256, 0, stream>>>(QKV, QKV + 8388608, Vt, cu, d_out,
                                                  Xatt, flagp);
    gemm_bt<<<dim3(8, 64), 256, 0, stream>>>(Xatt, Xatt, Xatt, Wp, biasArr, d_out, 3, 1,
                                             flagp);
}